// Round 3
// baseline (337.966 us; speedup 1.0000x reference)
//
#include <hip/hip_runtime.h>

// Layout (ALL float32 — reference output dtype is fp32):
//   out[0        .. 8388608)  quantized_st  [4,64,32,32,32]
//   out[8388608  .. 8519680)  embed_idx as float  [4,32,32,32]
//   out[8519680]              latent_loss scalar
#define HWD      32768            // 32*32*32
#define NC       64               // channels / embed dim
#define NE       512              // codebook entries
#define NPOS     131072           // 4 * HWD
#define OUT_IDX  8388608
#define OUT_LOSS 8519680

// 256 blocks x 512 threads, 1 thread per spatial position.
// LDS: full codebook (128 KB) + row norms. 130 KB static LDS ran fine in R1.
__global__ __launch_bounds__(512) void vq_fused(
    const float* __restrict__ x, const float* __restrict__ w,
    float* __restrict__ out, float* __restrict__ loss_acc)
{
    __shared__ float lw[NE * NC];   // 128 KB codebook
    __shared__ float wsq[NE];       // row squared norms
    __shared__ float wred[8];       // per-wave loss partials

    const int tid = threadIdx.x;

    // ---- stage codebook -> LDS, coalesced float4 ----
    const float4* w4  = (const float4*)w;
    float4*       lw4 = (float4*)lw;
#pragma unroll
    for (int k = 0; k < 16; ++k) lw4[tid + k * 512] = w4[tid + k * 512];

    // ---- row norms: thread t computes row t (global reads, L2-hot) ----
    {
        const float4* row = w4 + tid * 16;
        float s0 = 0.f, s1 = 0.f, s2 = 0.f, s3 = 0.f;
#pragma unroll
        for (int k = 0; k < 16; ++k) {
            float4 v = row[k];
            s0 = fmaf(v.x, v.x, s0); s1 = fmaf(v.y, v.y, s1);
            s2 = fmaf(v.z, v.z, s2); s3 = fmaf(v.w, v.w, s3);
        }
        wsq[tid] = (s0 + s1) + (s2 + s3);
    }
    __syncthreads();

    // ---- this thread's position vector (coalesced: lane <-> hwd) ----
    const int n   = blockIdx.x * 512 + tid;
    const int b   = n >> 15;
    const int hwd = n & (HWD - 1);
    const float* xp = x + (size_t)b * NC * HWD + hwd;

    float xr[NC];
#pragma unroll
    for (int c = 0; c < NC; ++c) xr[c] = xp[(size_t)c * HWD];
    float xsq = 0.f;
#pragma unroll
    for (int c = 0; c < NC; ++c) xsq = fmaf(xr[c], xr[c], xsq);

    // ---- argmin over 512 codes; LDS rows are wave-uniform -> broadcast ----
    float best = 3.402823466e38f;
    int   bidx = 0;
#pragma unroll 2
    for (int e = 0; e < NE; ++e) {
        const float4* row = (const float4*)(lw + e * NC);
        float p0 = 0.f, p1 = 0.f, p2 = 0.f, p3 = 0.f;
#pragma unroll
        for (int k = 0; k < 16; ++k) {
            float4 v = row[k];
            p0 = fmaf(xr[4 * k + 0], v.x, p0);
            p1 = fmaf(xr[4 * k + 1], v.y, p1);
            p2 = fmaf(xr[4 * k + 2], v.z, p2);
            p3 = fmaf(xr[4 * k + 3], v.w, p3);
        }
        const float dot = (p0 + p1) + (p2 + p3);
        const float d   = (xsq - 2.f * dot) + wsq[e];  // same shape as reference
        if (d < best) { best = d; bidx = e; }          // strict <: np.argmin first-index
    }

    // ---- epilogue: gather winning row from global (L1/L2-hot; LDS would
    //      64-way-conflict on divergent rows), write fp32 outputs ----
    const float4* wrow = (const float4*)(w + bidx * NC);
    float* o0 = out + (size_t)b * NC * HWD + hwd;
    float lsum = 0.f;
#pragma unroll
    for (int k = 0; k < 16; ++k) {
        float4 q = wrow[k];
        float qv[4] = { q.x, q.y, q.z, q.w };
#pragma unroll
        for (int j = 0; j < 4; ++j) {
            const int c = 4 * k + j;
            const float xv = xr[c];
            const float dq = qv[j] - xv;          // stop_gradient(q - x)
            lsum = fmaf(dq, dq, lsum);
            o0[(size_t)c * HWD] = dq + xv;        // (q-x)+x in fp32, same ops as np
        }
    }
    out[OUT_IDX + n] = (float)bidx;

    // ---- loss: wave shuffle -> block LDS -> one atomic per block ----
#pragma unroll
    for (int off = 32; off >= 1; off >>= 1) lsum += __shfl_down(lsum, off);
    if ((tid & 63) == 0) wred[tid >> 6] = lsum;
    __syncthreads();
    if (tid == 0) {
        float s = 0.f;
#pragma unroll
        for (int i = 0; i < 8; ++i) s += wred[i];
        atomicAdd(loss_acc, s);
    }
}

__global__ void vq_loss_finalize(const float* __restrict__ loss_acc,
                                 float* __restrict__ out)
{
    out[OUT_LOSS] = 0.25f * loss_acc[0] / 8388608.0f;
}

extern "C" void kernel_launch(void* const* d_in, const int* in_sizes, int n_in,
                              void* d_out, int out_size, void* d_ws, size_t ws_size,
                              hipStream_t stream)
{
    const float* x = (const float*)d_in[0];
    const float* w = (const float*)d_in[1];
    float* out = (float*)d_out;
    float* acc = (float*)d_ws;

    hipMemsetAsync(d_ws, 0, sizeof(float), stream);   // ws re-poisoned每launch
    vq_fused<<<256, 512, 0, stream>>>(x, w, out, acc);
    vq_loss_finalize<<<1, 1, 0, stream>>>(acc, out);
}

// Round 4
// 250.990 us; speedup vs baseline: 1.3465x; 1.3465x over previous
//
#include <hip/hip_runtime.h>

// Output layout (ALL float32):
//   out[0        .. 8388608)  quantized_st  [4,64,32,32,32]
//   out[8388608  .. 8519680)  embed_idx as float  [4,32,32,32]
//   out[8519680]              latent_loss scalar
#define HWD      32768            // 32*32*32
#define NC       64               // channels / embed dim
#define NE       512              // codebook entries
#define OUT_IDX  8388608
#define OUT_LOSS 8519680
#define TCODES   256              // codebook rows per LDS pass (64 KB)

// 256 blocks x 256 threads, P=2 positions per thread (512 pos/block).
// Codebook staged in two 64KB halves -> 2 blocks/CU, 8 waves/CU.
// Each broadcast ds_read_b128 now feeds 128 FMAs (2 positions) instead of 64,
// halving LDS-pipe demand per FMA: LDS ~576 cyc vs VALU ~560 cyc per code/CU.
__global__ __launch_bounds__(256, 2) void vq_fused(
    const float* __restrict__ x, const float* __restrict__ w,
    float* __restrict__ out, float* __restrict__ loss_acc)
{
    __shared__ float lw[TCODES * NC];   // 64 KB codebook half
    __shared__ float wsq[TCODES];       // row squared norms (this half)
    __shared__ float wred[4];           // per-wave loss partials

    const int tid = threadIdx.x;
    const int n0  = blockIdx.x * 512;          // first position of block
    const int b   = n0 >> 15;                  // batch (same for all 512)
    const int hwd = (n0 & (HWD - 1)) + tid;    // this thread's first position
    const float* xp = x + (size_t)b * NC * HWD + hwd;

    // ---- two position vectors in registers (coalesced: lane <-> hwd) ----
    float xr0[NC], xr1[NC];
#pragma unroll
    for (int c = 0; c < NC; ++c) {
        xr0[c] = xp[(size_t)c * HWD];
        xr1[c] = xp[(size_t)c * HWD + 256];
    }
    float xsq0 = 0.f, xsq1 = 0.f;
#pragma unroll
    for (int c = 0; c < NC; ++c) {
        xsq0 = fmaf(xr0[c], xr0[c], xsq0);
        xsq1 = fmaf(xr1[c], xr1[c], xsq1);
    }

    float best0 = 3.402823466e38f, best1 = 3.402823466e38f;
    int   bi0 = 0, bi1 = 0;

    for (int pass = 0; pass < 2; ++pass) {
        if (pass) __syncthreads();   // protect lw while previous pass computes

        // ---- stage 256 codebook rows -> LDS, coalesced float4 ----
        const float4* wt = (const float4*)(w + pass * TCODES * NC);
        float4*       l4 = (float4*)lw;
#pragma unroll
        for (int k = 0; k < 16; ++k) l4[tid + k * 256] = wt[tid + k * 256];

        // ---- row norms: thread t computes row t of this half ----
        {
            const float4* row = wt + tid * 16;
            float s0 = 0.f, s1 = 0.f, s2 = 0.f, s3 = 0.f;
#pragma unroll
            for (int k = 0; k < 16; ++k) {
                float4 v = row[k];
                s0 = fmaf(v.x, v.x, s0); s1 = fmaf(v.y, v.y, s1);
                s2 = fmaf(v.z, v.z, s2); s3 = fmaf(v.w, v.w, s3);
            }
            wsq[tid] = (s0 + s1) + (s2 + s3);
        }
        __syncthreads();

        // ---- 256 codes: wave-uniform LDS broadcast, 2 positions per read ----
#pragma unroll 2
        for (int e = 0; e < TCODES; ++e) {
            const float4* row = (const float4*)(lw + e * NC);
            float a0 = 0.f, a1 = 0.f;   // pos0 partials
            float c0 = 0.f, c1 = 0.f;   // pos1 partials
#pragma unroll
            for (int k = 0; k < 16; ++k) {
                float4 v = row[k];
                a0 = fmaf(xr0[4 * k + 0], v.x, a0);
                a1 = fmaf(xr0[4 * k + 1], v.y, a1);
                a0 = fmaf(xr0[4 * k + 2], v.z, a0);
                a1 = fmaf(xr0[4 * k + 3], v.w, a1);
                c0 = fmaf(xr1[4 * k + 0], v.x, c0);
                c1 = fmaf(xr1[4 * k + 1], v.y, c1);
                c0 = fmaf(xr1[4 * k + 2], v.z, c0);
                c1 = fmaf(xr1[4 * k + 3], v.w, c1);
            }
            const float d0 = (xsq0 - 2.f * (a0 + a1)) + wsq[e];
            const float d1 = (xsq1 - 2.f * (c0 + c1)) + wsq[e];
            const int   ge = pass * TCODES + e;
            if (d0 < best0) { best0 = d0; bi0 = ge; }  // strict <: np first-index
            if (d1 < best1) { best1 = d1; bi1 = ge; }
        }
    }

    // ---- epilogue: gather winning rows from global (L2-hot), write fp32 ----
    float* o0 = out + (size_t)b * NC * HWD + hwd;
    float lsum = 0.f;
    {
        const float4* r0 = (const float4*)(w + bi0 * NC);
        const float4* r1 = (const float4*)(w + bi1 * NC);
#pragma unroll
        for (int k = 0; k < 16; ++k) {
            float4 q0 = r0[k], q1 = r1[k];
            float qv0[4] = { q0.x, q0.y, q0.z, q0.w };
            float qv1[4] = { q1.x, q1.y, q1.z, q1.w };
#pragma unroll
            for (int j = 0; j < 4; ++j) {
                const int c = 4 * k + j;
                const float dv0 = qv0[j] - xr0[c];
                const float dv1 = qv1[j] - xr1[c];
                lsum = fmaf(dv0, dv0, lsum);
                lsum = fmaf(dv1, dv1, lsum);
                o0[(size_t)c * HWD]       = dv0 + xr0[c];  // (q-x)+x as np
                o0[(size_t)c * HWD + 256] = dv1 + xr1[c];
            }
        }
    }
    const int n = b * HWD + hwd;           // global position index (pos0)
    out[OUT_IDX + n]       = (float)bi0;
    out[OUT_IDX + n + 256] = (float)bi1;

    // ---- loss: wave shuffle -> block LDS -> one atomic per block ----
#pragma unroll
    for (int off = 32; off >= 1; off >>= 1) lsum += __shfl_down(lsum, off);
    if ((tid & 63) == 0) wred[tid >> 6] = lsum;
    __syncthreads();
    if (tid == 0)
        atomicAdd(loss_acc, (wred[0] + wred[1]) + (wred[2] + wred[3]));
}

__global__ void vq_loss_finalize(const float* __restrict__ loss_acc,
                                 float* __restrict__ out)
{
    out[OUT_LOSS] = 0.25f * loss_acc[0] / 8388608.0f;
}

extern "C" void kernel_launch(void* const* d_in, const int* in_sizes, int n_in,
                              void* d_out, int out_size, void* d_ws, size_t ws_size,
                              hipStream_t stream)
{
    const float* x = (const float*)d_in[0];
    const float* w = (const float*)d_in[1];
    float* out = (float*)d_out;
    float* acc = (float*)d_ws;

    hipMemsetAsync(d_ws, 0, sizeof(float), stream);
    vq_fused<<<256, 256, 0, stream>>>(x, w, out, acc);
    vq_loss_finalize<<<1, 1, 0, stream>>>(acc, out);
}